// Round 5
// baseline (348.547 us; speedup 1.0000x reference)
//
#include <hip/hip_runtime.h>

typedef _Float16 half_t;
typedef _Float16 half8 __attribute__((ext_vector_type(8)));
typedef float    floatx4 __attribute__((ext_vector_type(4)));

#define V1     32001
#define EMBD   100
#define UNITS  1000
#define SEQ    25
#define NROWS  1600
#define KPAD   32032          // ET padded K (f16); kA uses k<32000, fixup adds 32000
#define HSTR   1024           // h1h / MbT padded K (1000 data + ones col + pad)
#define NKB    36             // P slabs (kq count); 35*28+20 = 1000 k-units
#define KUQ    28             // k-units per wave (last kq: 20)
#define PROWS  1024           // P slab rows (m padded to 1024)

// ===========================================================================
// kPre: fused independent producers, dispatched by blockIdx range:
//   [0,501)      kT : E[32001][100] f32 -> ET[100][KPAD] f16 (k>=32000 zeroed)
//   [501,757)    kV : vvec[e] = sum_j fc_b[j]*emb[j][e]  (atomic, 512 slices)
//   [757,1557)   kB : GRU gates (h=0) -> h1h[1600][HSTR] f16 (+ones col 1000)
// ===========================================================================
__global__ __launch_bounds__(256) void kPre(
    const float* __restrict__ E, half_t* __restrict__ ET,
    const float* __restrict__ fcb, float* __restrict__ vvec,
    const int* __restrict__ target, const int* __restrict__ stok,
    const float* __restrict__ K, const float* __restrict__ bias,
    half_t* __restrict__ h1h)
{
    __shared__ char smem[100 * 66 * sizeof(half_t)];
    const int tid = threadIdx.x;
    const int bid = blockIdx.x;

    if (bid < 501) {                       // ---- kT ----
        half_t* lds = (half_t*)smem;
        const int k0 = bid * 64;
        const int e  = tid & 127;
        const int kh = tid >> 7;
        for (int kk = kh; kk < 64; kk += 2) {
            const int k = k0 + kk;
            float v = 0.f;
            if (k < 32000 && e < 100) v = E[k * 100 + e];
            if (e < 100) lds[e * 66 + kk] = (half_t)v;
        }
        __syncthreads();
        const int kl = tid & 63;
        const int eh = tid >> 6;
        if (k0 + kl < KPAD) {
            for (int ee = eh; ee < 100; ee += 4)
                ET[(long)ee * KPAD + k0 + kl] = lds[ee * 66 + kl];
        }
        return;
    }

    if (bid < 757) {                       // ---- kV ----
        const int e  = tid & 127;
        const int g  = tid >> 7;
        const int ec = min(e, 99);
        const int slice = (bid - 501) * 2 + g;
        const int chunk = (V1 + 511) / 512;
        const int j0 = slice * chunk;
        const int j1 = min(j0 + chunk, V1);
        float acc = 0.f;
        for (int j = j0; j < j1; ++j)
            acc += fcb[j] * E[j * 100 + ec];
        if (e < 100) atomicAdd(&vvec[e], acc);
        return;
    }

    // ---- kB ----
    float (*xs)[100] = (float(*)[100])smem;
    __shared__ int msk[8];
    const int b3    = bid - 757;
    const int rg    = b3 % 200;
    const int uc    = b3 / 200;
    const int ibase = rg * 8;
    {
        const int r = tid >> 5, c = tid & 31;
        const int i = ibase + r;
        const int bb = i / SEQ, t = i - bb * SEQ;
        const int token = (t == 0) ? stok[0] : target[bb * SEQ + t - 1];
        if (c == 0) msk[r] = (token != 0);
        for (int cc = c; cc < 100; cc += 32)
            xs[r][cc] = E[token * 100 + cc];
    }
    __syncthreads();

    const int u = uc * 256 + tid;
    if (u < UNITS) {
        float az[8], ar[8], ah[8];
#pragma unroll
        for (int r = 0; r < 8; ++r) { az[r] = 0.f; ar[r] = 0.f; ah[r] = 0.f; }
#pragma unroll 4
        for (int k = 0; k < 100; ++k) {
            const float wz = K[k * 3000 + u];
            const float wr = K[k * 3000 + 1000 + u];
            const float wh = K[k * 3000 + 2000 + u];
#pragma unroll
            for (int r = 0; r < 8; ++r) {
                const float x = xs[r][k];
                az[r] += x * wz;
                ar[r] += x * wr;
                ah[r] += x * wh;
            }
        }
        const float* b0 = bias;
        const float* b1 = bias + 3000;
        const float bz  = b0[u] + b1[u];
        const float br  = b0[1000 + u] + b1[1000 + u];
        const float bh0 = b0[2000 + u];
        const float bh1 = b1[2000 + u];
#pragma unroll
        for (int r = 0; r < 8; ++r) {
            const float z   = 1.f / (1.f + __expf(-(az[r] + bz)));
            const float rg_ = 1.f / (1.f + __expf(-(ar[r] + br)));
            const float pre = ah[r] + bh0 + rg_ * bh1;
            const float ex  = __expf(2.f * pre);
            const float hh  = 1.f - 2.f / (ex + 1.f);
            h1h[(ibase + r) * HSTR + u] = (half_t)(msk[r] ? (1.f - z) * hh : 0.f);
        }
    } else {
        const half_t cv = (half_t)((u == 1000) ? 1.f : 0.f);
#pragma unroll
        for (int r = 0; r < 8; ++r)
            h1h[(ibase + r) * HSTR + u] = cv;
    }
}

// ===========================================================================
// kA: P[kq][1024][100] = W-chunk @ E via f16 MFMA 16x16x32.
// Grid dim3(16 mgrp, 36 kq); block = 4 INDEPENDENT waves (different 16-row
// m-tiles, same k range). Wave: 16m x 112n x 28 k-units, NB=4 units in
// flight (~36 outstanding loads). No LDS / sync / atomics: each wave writes
// its exclusive P rows.
// ===========================================================================
__global__ __launch_bounds__(256) void kA(const float* __restrict__ W,
                                          const half_t* __restrict__ ET,
                                          float* __restrict__ P)
{
    const int tid   = threadIdx.x;
    const int lane  = tid & 63;
    const int wv    = tid >> 6;
    const int mgrp  = blockIdx.x;          // 0..15  (64 rows each)
    const int kq    = blockIdx.y;          // 0..35
    const int row16 = lane & 15;
    const int quad  = lane >> 4;

    const int m  = mgrp * 64 + wv * 16 + row16;
    const int mc = min(m, UNITS - 1);      // padded rows clamp (discarded later)
    const float* wrow = W + (long)mc * V1;

    const int wb = kq * KUQ;
    const int we = min(wb + KUQ, 1000);    // 28 or 20 units: both %4 == 0

    floatx4 acc[7];
#pragma unroll
    for (int t = 0; t < 7; ++t) acc[t] = (floatx4){0.f, 0.f, 0.f, 0.f};

    const half_t* bb[7];
#pragma unroll
    for (int t = 0; t < 7; ++t) {
        const int nc = min(t * 16 + row16, 99);
        bb[t] = ET + (long)nc * KPAD + quad * 8;
    }

    int un = wb;
    for (; un + 4 <= we; un += 4) {        // NB=4: 4 indep units in flight
        float fa[4][8];
        half8 vb[4][7];
#pragma unroll
        for (int j = 0; j < 4; ++j) {
            const int k0 = (un + j) * 32 + quad * 8;
            __builtin_memcpy(&fa[j][0], wrow + k0, 32);
        }
#pragma unroll
        for (int j = 0; j < 4; ++j) {
            const int koff = (un + j) * 32;
#pragma unroll
            for (int t = 0; t < 7; ++t)
                vb[j][t] = *(const half8*)(bb[t] + koff);
        }
#pragma unroll
        for (int j = 0; j < 4; ++j) {
            half8 a;
#pragma unroll
            for (int q = 0; q < 8; ++q) a[q] = (half_t)fa[j][q];
#pragma unroll
            for (int t = 0; t < 7; ++t)
                acc[t] = __builtin_amdgcn_mfma_f32_16x16x32_f16(a, vb[j][t], acc[t], 0, 0, 0);
        }
    }
    for (; un < we; ++un) {                // safety tail (unused: counts %4==0)
        const int k0 = un * 32 + quad * 8;
        float f0[8];
        __builtin_memcpy(f0, wrow + k0, 32);
        half8 a;
#pragma unroll
        for (int q = 0; q < 8; ++q) a[q] = (half_t)f0[q];
#pragma unroll
        for (int t = 0; t < 7; ++t) {
            const half8 b = *(const half8*)(bb[t] + un * 32);
            acc[t] = __builtin_amdgcn_mfma_f32_16x16x32_f16(a, b, acc[t], 0, 0, 0);
        }
    }

    float* Pk = P + (long)kq * (PROWS * 100);
    const int orow0 = mgrp * 64 + wv * 16 + quad * 4;  // C/D: row=(lane>>4)*4+r
#pragma unroll
    for (int t = 0; t < 7; ++t) {
        const int col = t * 16 + row16;                // C/D: col=lane&15
        if (col < 100) {
#pragma unroll
            for (int r = 0; r < 4; ++r)
                Pk[(orow0 + r) * 100 + col] = acc[t][r];
        }
    }
}

// ===========================================================================
// kPost: MbT[100][HSTR] f16:
//   kk<1000 : sum_kq P[kq][kk][e]  +  W[kk][32000]*E[32000][e]  (k-tail fixup)
//   kk==1000: vvec[e];   else 0
// ===========================================================================
__global__ __launch_bounds__(256) void kPost(const float* __restrict__ P,
                                             const float* __restrict__ W,
                                             const float* __restrict__ E,
                                             const float* __restrict__ vvec,
                                             half_t* __restrict__ MbT)
{
    const int idx = blockIdx.x * 256 + threadIdx.x;   // < 1024*100
    const int kk  = idx / 100;
    const int e   = idx - kk * 100;
    float s;
    if (kk < 1000) {
        s = 0.f;
#pragma unroll 4
        for (int kb = 0; kb < NKB; ++kb)
            s += P[(long)kb * (PROWS * 100) + kk * 100 + e];
        s += W[(long)kk * V1 + 32000] * E[32000 * 100 + e];
    } else if (kk == 1000) {
        s = vvec[e];
    } else {
        s = 0.f;
    }
    MbT[e * HSTR + kk] = (half_t)s;
}

// ===========================================================================
// kC: out[1600][100] = [h1|1] @ [M;v] via f16 MFMA.
// Block = 4 waves splitting K (8 units each), LDS reduce, wave 0 writes.
// ===========================================================================
__global__ __launch_bounds__(256) void kC(const half_t* __restrict__ h1h,
                                          const half_t* __restrict__ MbT,
                                          float* __restrict__ out)
{
    __shared__ float red[3][64][29];
    const int tid   = threadIdx.x;
    const int lane  = tid & 63;
    const int wv    = tid >> 6;
    const int rb    = blockIdx.x;          // 0..99
    const int row16 = lane & 15;
    const int quad  = lane >> 4;

    const half_t* arow = h1h + (long)(rb * 16 + row16) * HSTR + quad * 8;
    const half_t* bbase[7];
#pragma unroll
    for (int t = 0; t < 7; ++t) {
        const int nc = min(t * 16 + row16, 99);
        bbase[t] = MbT + (long)nc * HSTR + quad * 8;
    }

    floatx4 acc[7];
#pragma unroll
    for (int t = 0; t < 7; ++t) acc[t] = (floatx4){0.f, 0.f, 0.f, 0.f};

    const int wb = wv * 8;
#pragma unroll 2
    for (int un = wb; un < wb + 8; ++un) {
        const half8 a = *(const half8*)(arow + un * 32);
#pragma unroll
        for (int t = 0; t < 7; ++t) {
            const half8 b = *(const half8*)(bbase[t] + un * 32);
            acc[t] = __builtin_amdgcn_mfma_f32_16x16x32_f16(a, b, acc[t], 0, 0, 0);
        }
    }

    if (wv > 0) {
#pragma unroll
        for (int t = 0; t < 7; ++t)
#pragma unroll
            for (int r = 0; r < 4; ++r)
                red[wv - 1][lane][t * 4 + r] = acc[t][r];
    }
    __syncthreads();
    if (wv == 0) {
        const int orow0 = rb * 16 + quad * 4;
#pragma unroll
        for (int t = 0; t < 7; ++t) {
            const int col = t * 16 + row16;
            if (col < 100) {
#pragma unroll
                for (int r = 0; r < 4; ++r) {
                    const int i = t * 4 + r;
                    out[(orow0 + r) * 100 + col] = acc[t][r] + red[0][lane][i]
                        + red[1][lane][i] + red[2][lane][i];
                }
            }
        }
    }
}

// ===========================================================================
extern "C" void kernel_launch(void* const* d_in, const int* in_sizes, int n_in,
                              void* d_out, int out_size, void* d_ws, size_t ws_size,
                              hipStream_t stream)
{
    const int*   target     = (const int*)d_in[1];
    const int*   start_tok  = (const int*)d_in[2];
    const float* emb        = (const float*)d_in[3];
    const float* dec_kernel = (const float*)d_in[7];
    const float* dec_bias   = (const float*)d_in[9];
    const float* fc_w       = (const float*)d_in[10];
    const float* fc_b       = (const float*)d_in[11];

    float*  vvec = (float*)d_ws;                         // 128 f32
    half_t* ET   = (half_t*)(vvec + 128);                // 100*KPAD f16 (6.4 MB)
    half_t* h1h  = ET + (size_t)100 * KPAD;              // 1600*HSTR f16 (3.3 MB)
    half_t* MbT  = h1h + (size_t)NROWS * HSTR;           // 100*HSTR f16 (0.2 MB)
    float*  P    = (float*)(MbT + (size_t)100 * HSTR);   // 36*1024*100 f32 (14.8 MB)
    float*  out  = (float*)d_out;

    hipMemsetAsync(vvec, 0, 128 * sizeof(float), stream);

    kPre<<<1557, 256, 0, stream>>>(emb, ET, fc_b, vvec, target, start_tok,
                                   dec_kernel, dec_bias, h1h);
    kA<<<dim3(16, NKB), 256, 0, stream>>>(fc_w, ET, P);
    kPost<<<(PROWS * 100) / 256, 256, 0, stream>>>(P, fc_w, emb, vvec, MbT);
    kC<<<100, 256, 0, stream>>>(h1h, MbT, out);
}

// Round 6
// 297.987 us; speedup vs baseline: 1.1697x; 1.1697x over previous
//
#include <hip/hip_runtime.h>

typedef _Float16 half_t;
typedef _Float16 half8 __attribute__((ext_vector_type(8)));
typedef float    floatx4 __attribute__((ext_vector_type(4)));

#define V1     32001
#define EMBD   100
#define UNITS  1000
#define SEQ    25
#define NROWS  1600
#define HSTR   1024           // h1h / MbT padded K (1000 data + ones col + pad)
#define NKB    63             // P slabs; units per kq = 16 (last kq: 8)
#define UPQ    16             // k-units (of 32) per kq block
#define BROWS  128            // padded n-rows per ETu tile (100 data + 28 zero)
#define BSTR   40             // LDS B row stride in halfs (80 B, 2-way = free)

// ===========================================================================
// kPre: fused independent producers, dispatched by blockIdx range:
//   [0,500)      kT : E[32000][100] f32 -> ETu[1000][128][32] f16 unit-major
//   [500,756)    kV : vvec[e] = sum_j fc_b[j]*emb[j][e]
//   [756,1556)   kB : GRU gates (h=0) -> h1h[1600][HSTR] f16 (+ones col 1000)
// ===========================================================================
__global__ __launch_bounds__(256) void kPre(
    const float* __restrict__ E, half_t* __restrict__ ETu,
    const float* __restrict__ fcb, float* __restrict__ vvec,
    const int* __restrict__ target, const int* __restrict__ stok,
    const float* __restrict__ K, const float* __restrict__ bias,
    half_t* __restrict__ h1h)
{
    __shared__ char smem[100 * 66 * sizeof(half_t)];
    const int tid = threadIdx.x;
    const int bid = blockIdx.x;

    if (bid < 500) {                       // ---- kT ----
        half_t* lds = (half_t*)smem;
        const int k0 = bid * 64;           // 64 k's = 2 units
        const int e  = tid & 127;
        const int kh = tid >> 7;
        for (int kk = kh; kk < 64; kk += 2) {
            const int k = k0 + kk;
            if (e < 100) lds[e * 66 + kk] = (half_t)E[k * 100 + e];
        }
        __syncthreads();
        const int kl   = tid & 63;
        const int eh   = tid >> 6;
        const int unit = (k0 + kl) >> 5;
        const int kc   = kl & 31;
        half_t* dst = ETu + (long)unit * (BROWS * 32) + kc;
        for (int ee = eh; ee < BROWS; ee += 4)
            dst[ee * 32] = (ee < 100) ? lds[ee * 66 + kl] : (half_t)0.f;
        return;
    }

    if (bid < 756) {                       // ---- kV ----
        const int e  = tid & 127;
        const int g  = tid >> 7;
        const int ec = min(e, 99);
        const int slice = (bid - 500) * 2 + g;
        const int chunk = (V1 + 511) / 512;
        const int j0 = slice * chunk;
        const int j1 = min(j0 + chunk, V1);
        float acc = 0.f;
        for (int j = j0; j < j1; ++j)
            acc += fcb[j] * E[j * 100 + ec];
        if (e < 100) atomicAdd(&vvec[e], acc);
        return;
    }

    // ---- kB ----
    float (*xs)[100] = (float(*)[100])smem;
    __shared__ int msk[8];
    const int b3    = bid - 756;
    const int rg    = b3 % 200;
    const int uc    = b3 / 200;
    const int ibase = rg * 8;
    {
        const int r = tid >> 5, c = tid & 31;
        const int i = ibase + r;
        const int bb = i / SEQ, t = i - bb * SEQ;
        const int token = (t == 0) ? stok[0] : target[bb * SEQ + t - 1];
        if (c == 0) msk[r] = (token != 0);
        for (int cc = c; cc < 100; cc += 32)
            xs[r][cc] = E[token * 100 + cc];
    }
    __syncthreads();

    const int u = uc * 256 + tid;
    if (u < UNITS) {
        float az[8], ar[8], ah[8];
#pragma unroll
        for (int r = 0; r < 8; ++r) { az[r] = 0.f; ar[r] = 0.f; ah[r] = 0.f; }
#pragma unroll 4
        for (int k = 0; k < 100; ++k) {
            const float wz = K[k * 3000 + u];
            const float wr = K[k * 3000 + 1000 + u];
            const float wh = K[k * 3000 + 2000 + u];
#pragma unroll
            for (int r = 0; r < 8; ++r) {
                const float x = xs[r][k];
                az[r] += x * wz;
                ar[r] += x * wr;
                ah[r] += x * wh;
            }
        }
        const float* b0 = bias;
        const float* b1 = bias + 3000;
        const float bz  = b0[u] + b1[u];
        const float br  = b0[1000 + u] + b1[1000 + u];
        const float bh0 = b0[2000 + u];
        const float bh1 = b1[2000 + u];
#pragma unroll
        for (int r = 0; r < 8; ++r) {
            const float z   = 1.f / (1.f + __expf(-(az[r] + bz)));
            const float rg_ = 1.f / (1.f + __expf(-(ar[r] + br)));
            const float pre = ah[r] + bh0 + rg_ * bh1;
            const float ex  = __expf(2.f * pre);
            const float hh  = 1.f - 2.f / (ex + 1.f);
            h1h[(ibase + r) * HSTR + u] = (half_t)(msk[r] ? (1.f - z) * hh : 0.f);
        }
    } else {
        const half_t cv = (half_t)((u == 1000) ? 1.f : 0.f);
#pragma unroll
        for (int r = 0; r < 8; ++r)
            h1h[(ibase + r) * HSTR + u] = cv;
    }
}

// ===========================================================================
// kA: P[kq][1024][100] (f16) = W-chunk @ E via f16 MFMA 16x16x32.
// Grid dim3(16 mgrp, 63 kq). Block = 4 waves x 16 m-rows (64 rows), 7 n-tiles.
// B staged unit-by-unit into double-buffered LDS (shared by all 4 waves),
// A direct-to-register with depth-1 prefetch. One barrier per unit.
// ===========================================================================
__global__ __launch_bounds__(256) void kA(const float* __restrict__ W,
                                          const half_t* __restrict__ ETu,
                                          half_t* __restrict__ P)
{
    __shared__ half_t Bs[2][BROWS * BSTR];      // 2 x 10.0 KB
    const int tid   = threadIdx.x;
    const int lane  = tid & 63;
    const int wv    = tid >> 6;
    const int mgrp  = blockIdx.x;               // 0..15
    const int kq    = blockIdx.y;               // 0..62
    const int row16 = lane & 15;
    const int quad  = lane >> 4;

    const int ub = kq * UPQ;
    const int nu = min(UPQ, UNITS - ub);        // 16 (last kq: 8)

    const int m  = mgrp * 64 + wv * 16 + row16;
    const int mc = min(m, UNITS - 1);
    const float* wrow = W + (long)mc * V1;

    // B staging mapping: thread covers halfs [tid*8,+8) and [2048+tid*8,+8)
    // of the 4096-half unit tile; LDS rows padded to BSTR.
    const int srow  = tid >> 2;
    const int scol  = (tid & 3) * 8;
    const int soff0 = srow * BSTR + scol;
    const int soff1 = (64 + srow) * BSTR + scol;
    const int goff0 = tid * 8;
    const int goff1 = 2048 + tid * 8;

    floatx4 acc[7];
#pragma unroll
    for (int t = 0; t < 7; ++t) acc[t] = (floatx4){0.f, 0.f, 0.f, 0.f};

    // prologue: prefetch unit ub
    half8 rb0 = *(const half8*)(ETu + (long)ub * (BROWS * 32) + goff0);
    half8 rb1 = *(const half8*)(ETu + (long)ub * (BROWS * 32) + goff1);
    float fa[8];
    __builtin_memcpy(fa, wrow + ub * 32 + quad * 8, 32);

    for (int i = 0; i < nu; ++i) {
        // stage current B into this iteration's buffer
        *(half8*)(&Bs[i & 1][soff0]) = rb0;
        *(half8*)(&Bs[i & 1][soff1]) = rb1;
        // convert current A fragment
        half8 a;
#pragma unroll
        for (int q = 0; q < 8; ++q) a[q] = (half_t)fa[q];
        // prefetch next unit (drained at the barrier; block-level overlap hides it)
        if (i + 1 < nu) {
            const long nt = (long)(ub + i + 1) * (BROWS * 32);
            rb0 = *(const half8*)(ETu + nt + goff0);
            rb1 = *(const half8*)(ETu + nt + goff1);
            __builtin_memcpy(fa, wrow + (ub + i + 1) * 32 + quad * 8, 32);
        }
        __syncthreads();
        // compute: 7 n-tiles from LDS (double buffer => no trailing barrier;
        // buffer i&1 is next rewritten at i+2, after barrier i+1)
        const half_t* bp = &Bs[i & 1][row16 * BSTR + quad * 8];
#pragma unroll
        for (int t = 0; t < 7; ++t) {
            const half8 b = *(const half8*)(bp + t * 16 * BSTR);
            acc[t] = __builtin_amdgcn_mfma_f32_16x16x32_f16(a, b, acc[t], 0, 0, 0);
        }
    }

    half_t* Pk = P + (long)kq * (1024 * 100);
    const int orow0 = mgrp * 64 + wv * 16 + quad * 4;   // C/D: row=(lane>>4)*4+r
#pragma unroll
    for (int t = 0; t < 7; ++t) {
        const int col = t * 16 + row16;                 // C/D: col=lane&15
        if (col < 100) {
#pragma unroll
            for (int r = 0; r < 4; ++r)
                Pk[(orow0 + r) * 100 + col] = (half_t)acc[t][r];
        }
    }
}

// ===========================================================================
// kPost: MbT[100][HSTR] f16:
//   kk<1000 : sum_kq P[kq][kk][e] (f16 slabs) + W[kk][32000]*E[32000][e]
//   kk==1000: vvec[e];   else 0
// ===========================================================================
__global__ __launch_bounds__(256) void kPost(const half_t* __restrict__ P,
                                             const float* __restrict__ W,
                                             const float* __restrict__ E,
                                             const float* __restrict__ vvec,
                                             half_t* __restrict__ MbT)
{
    const int idx = blockIdx.x * 256 + threadIdx.x;   // < 1024*100
    const int kk  = idx / 100;
    const int e   = idx - kk * 100;
    float s;
    if (kk < 1000) {
        s = 0.f;
#pragma unroll 9
        for (int kb = 0; kb < NKB; ++kb)
            s += (float)P[(long)kb * (1024 * 100) + kk * 100 + e];
        s += W[(long)kk * V1 + 32000] * E[32000 * 100 + e];
    } else if (kk == 1000) {
        s = vvec[e];
    } else {
        s = 0.f;
    }
    MbT[e * HSTR + kk] = (half_t)s;
}

// ===========================================================================
// kC: out[1600][100] = [h1|1] @ [M;v] via f16 MFMA.
// Grid (100 rb, 4 ks): block = 4 waves x 2 units (ks covers 8 of 32 units),
// LDS reduce across waves, wave 0 atomicAdds into zero-initialized out.
// ===========================================================================
__global__ __launch_bounds__(256) void kC(const half_t* __restrict__ h1h,
                                          const half_t* __restrict__ MbT,
                                          float* __restrict__ out)
{
    __shared__ float red[3][64][29];
    const int tid   = threadIdx.x;
    const int lane  = tid & 63;
    const int wv    = tid >> 6;
    const int rb    = blockIdx.x;          // 0..99
    const int ks    = blockIdx.y;          // 0..3
    const int row16 = lane & 15;
    const int quad  = lane >> 4;

    const half_t* arow = h1h + (long)(rb * 16 + row16) * HSTR + quad * 8;
    const half_t* bbase[7];
#pragma unroll
    for (int t = 0; t < 7; ++t) {
        const int nc = min(t * 16 + row16, 99);
        bbase[t] = MbT + (long)nc * HSTR + quad * 8;
    }

    floatx4 acc[7];
#pragma unroll
    for (int t = 0; t < 7; ++t) acc[t] = (floatx4){0.f, 0.f, 0.f, 0.f};

    const int wb = ks * 8 + wv * 2;
#pragma unroll
    for (int un = wb; un < wb + 2; ++un) {
        const half8 a = *(const half8*)(arow + un * 32);
#pragma unroll
        for (int t = 0; t < 7; ++t) {
            const half8 b = *(const half8*)(bbase[t] + un * 32);
            acc[t] = __builtin_amdgcn_mfma_f32_16x16x32_f16(a, b, acc[t], 0, 0, 0);
        }
    }

    if (wv > 0) {
#pragma unroll
        for (int t = 0; t < 7; ++t)
#pragma unroll
            for (int r = 0; r < 4; ++r)
                red[wv - 1][lane][t * 4 + r] = acc[t][r];
    }
    __syncthreads();
    if (wv == 0) {
        const int orow0 = rb * 16 + quad * 4;
#pragma unroll
        for (int t = 0; t < 7; ++t) {
            const int col = t * 16 + row16;
            if (col < 100) {
#pragma unroll
                for (int r = 0; r < 4; ++r) {
                    const int i = t * 4 + r;
                    const float s = acc[t][r] + red[0][lane][i]
                                  + red[1][lane][i] + red[2][lane][i];
                    atomicAdd(&out[(orow0 + r) * 100 + col], s);
                }
            }
        }
    }
}

// ===========================================================================
extern "C" void kernel_launch(void* const* d_in, const int* in_sizes, int n_in,
                              void* d_out, int out_size, void* d_ws, size_t ws_size,
                              hipStream_t stream)
{
    const int*   target     = (const int*)d_in[1];
    const int*   start_tok  = (const int*)d_in[2];
    const float* emb        = (const float*)d_in[3];
    const float* dec_kernel = (const float*)d_in[7];
    const float* dec_bias   = (const float*)d_in[9];
    const float* fc_w       = (const float*)d_in[10];
    const float* fc_b       = (const float*)d_in[11];

    float*  vvec = (float*)d_ws;                         // 128 f32 (512 B)
    half_t* ETu  = (half_t*)(vvec + 128);                // 1000*128*32 f16 (8.19 MB)
    half_t* h1h  = ETu + (size_t)UNITS * (BROWS * 32);   // 1600*HSTR f16 (3.28 MB)
    half_t* MbT  = h1h + (size_t)NROWS * HSTR;           // 100*HSTR f16 (0.20 MB)
    half_t* P    = MbT + (size_t)100 * HSTR;             // 63*1024*100 f16 (12.9 MB)
    float*  out  = (float*)d_out;                        // total ws ~23.4 MiB

    hipMemsetAsync(vvec, 0, 128 * sizeof(float), stream);
    hipMemsetAsync(out, 0, (size_t)NROWS * EMBD * sizeof(float), stream);

    kPre<<<1556, 256, 0, stream>>>(emb, ETu, fc_b, vvec, target, start_tok,
                                   dec_kernel, dec_bias, h1h);
    kA<<<dim3(16, NKB), 256, 0, stream>>>(fc_w, ETu, P);
    kPost<<<(1024 * 100) / 256, 256, 0, stream>>>(P, fc_w, emb, vvec, MbT);
    kC<<<dim3(100, 4), 256, 0, stream>>>(h1h, MbT, out);
}

// Round 7
// 293.504 us; speedup vs baseline: 1.1875x; 1.0153x over previous
//
#include <hip/hip_runtime.h>

typedef _Float16 half_t;
typedef _Float16 half8 __attribute__((ext_vector_type(8)));
typedef float    floatx4 __attribute__((ext_vector_type(4)));

#define V1     32001
#define EMBD   100
#define UNITS  1000
#define SEQ    25
#define NROWS  1600
#define HSTR   1024           // h1h / MbT padded K (1000 data + ones col + pad)
#define NKB    63             // P slabs; units per kq = 16 (last kq: 8)
#define UPQ    16             // k-units (of 32) per kq block
#define BROWS  128            // padded n-rows per ETu tile (100 data + 28 zero)
#define BSTR   40             // LDS B row stride in halfs (80 B, 2-way = free)

// ===========================================================================
// kPre: fused independent producers, dispatched by blockIdx range:
//   [0,500)      kT : E[32000][100] f32 -> ETu[1000][128][32] f16 unit-major
//   [500,756)    kV : vvec[e] = sum_j fc_b[j]*emb[j][e]
//   [756,1556)   kB : GRU gates (h=0) -> h1h[1600][HSTR] f16 (+ones col 1000)
// ===========================================================================
__global__ __launch_bounds__(256) void kPre(
    const float* __restrict__ E, half_t* __restrict__ ETu,
    const float* __restrict__ fcb, float* __restrict__ vvec,
    const int* __restrict__ target, const int* __restrict__ stok,
    const float* __restrict__ K, const float* __restrict__ bias,
    half_t* __restrict__ h1h)
{
    __shared__ char smem[100 * 66 * sizeof(half_t)];
    const int tid = threadIdx.x;
    const int bid = blockIdx.x;

    if (bid < 500) {                       // ---- kT ----
        half_t* lds = (half_t*)smem;
        const int k0 = bid * 64;           // 64 k's = 2 units
        const int e  = tid & 127;
        const int kh = tid >> 7;
        for (int kk = kh; kk < 64; kk += 2) {
            const int k = k0 + kk;
            if (e < 100) lds[e * 66 + kk] = (half_t)E[k * 100 + e];
        }
        __syncthreads();
        const int kl   = tid & 63;
        const int eh   = tid >> 6;
        const int unit = (k0 + kl) >> 5;
        const int kc   = kl & 31;
        half_t* dst = ETu + (long)unit * (BROWS * 32) + kc;
        for (int ee = eh; ee < BROWS; ee += 4)
            dst[ee * 32] = (ee < 100) ? lds[ee * 66 + kl] : (half_t)0.f;
        return;
    }

    if (bid < 756) {                       // ---- kV ----
        const int e  = tid & 127;
        const int g  = tid >> 7;
        const int ec = min(e, 99);
        const int slice = (bid - 500) * 2 + g;
        const int chunk = (V1 + 511) / 512;
        const int j0 = slice * chunk;
        const int j1 = min(j0 + chunk, V1);
        float acc = 0.f;
        for (int j = j0; j < j1; ++j)
            acc += fcb[j] * E[j * 100 + ec];
        if (e < 100) atomicAdd(&vvec[e], acc);
        return;
    }

    // ---- kB ----
    float (*xs)[100] = (float(*)[100])smem;
    __shared__ int msk[8];
    const int b3    = bid - 756;
    const int rg    = b3 % 200;
    const int uc    = b3 / 200;
    const int ibase = rg * 8;
    {
        const int r = tid >> 5, c = tid & 31;
        const int i = ibase + r;
        const int bb = i / SEQ, t = i - bb * SEQ;
        const int token = (t == 0) ? stok[0] : target[bb * SEQ + t - 1];
        if (c == 0) msk[r] = (token != 0);
        for (int cc = c; cc < 100; cc += 32)
            xs[r][cc] = E[token * 100 + cc];
    }
    __syncthreads();

    const int u = uc * 256 + tid;
    if (u < UNITS) {
        float az[8], ar[8], ah[8];
#pragma unroll
        for (int r = 0; r < 8; ++r) { az[r] = 0.f; ar[r] = 0.f; ah[r] = 0.f; }
#pragma unroll 4
        for (int k = 0; k < 100; ++k) {
            const float wz = K[k * 3000 + u];
            const float wr = K[k * 3000 + 1000 + u];
            const float wh = K[k * 3000 + 2000 + u];
#pragma unroll
            for (int r = 0; r < 8; ++r) {
                const float x = xs[r][k];
                az[r] += x * wz;
                ar[r] += x * wr;
                ah[r] += x * wh;
            }
        }
        const float* b0 = bias;
        const float* b1 = bias + 3000;
        const float bz  = b0[u] + b1[u];
        const float br  = b0[1000 + u] + b1[1000 + u];
        const float bh0 = b0[2000 + u];
        const float bh1 = b1[2000 + u];
#pragma unroll
        for (int r = 0; r < 8; ++r) {
            const float z   = 1.f / (1.f + __expf(-(az[r] + bz)));
            const float rg_ = 1.f / (1.f + __expf(-(ar[r] + br)));
            const float pre = ah[r] + bh0 + rg_ * bh1;
            const float ex  = __expf(2.f * pre);
            const float hh  = 1.f - 2.f / (ex + 1.f);
            h1h[(ibase + r) * HSTR + u] = (half_t)(msk[r] ? (1.f - z) * hh : 0.f);
        }
    } else {
        const half_t cv = (half_t)((u == 1000) ? 1.f : 0.f);
#pragma unroll
        for (int r = 0; r < 8; ++r)
            h1h[(ibase + r) * HSTR + u] = cv;
    }
}

// ===========================================================================
// kA: P[kq][1024][100] (f16) = W-chunk @ E via f16 MFMA 16x16x32.
// Grid dim3(16 mgrp, 63 kq). Block = 4 waves x 16 m-rows, 7 n-tiles.
// B staged TWO units per barrier into double-buffered LDS (8 barriers/block,
// 14 MFMAs between barriers), A direct-to-register with pair prefetch.
// ===========================================================================
__global__ __launch_bounds__(256) void kA(const float* __restrict__ W,
                                          const half_t* __restrict__ ETu,
                                          half_t* __restrict__ P)
{
    __shared__ half_t Bs[2][2][BROWS * BSTR];   // 2 bufs x 2 units x 10 KB
    const int tid   = threadIdx.x;
    const int lane  = tid & 63;
    const int wv    = tid >> 6;
    const int mgrp  = blockIdx.x;               // 0..15
    const int kq    = blockIdx.y;               // 0..62
    const int row16 = lane & 15;
    const int quad  = lane >> 4;

    const int ub = kq * UPQ;
    const int nu = min(UPQ, UNITS - ub);        // 16 (last kq: 8) — even
    const int np = nu >> 1;                     // unit pairs per block

    const int m  = mgrp * 64 + wv * 16 + row16;
    const int mc = min(m, UNITS - 1);
    const float* wrow = W + (long)mc * V1;

    // staging map: thread covers halfs [tid*8,+8) and [2048+tid*8,+8) of each
    // 4096-half unit tile; LDS rows padded to BSTR.
    const int srow  = tid >> 2;
    const int scol  = (tid & 3) * 8;
    const int soff0 = srow * BSTR + scol;
    const int soff1 = (64 + srow) * BSTR + scol;
    const int goff0 = tid * 8;
    const int goff1 = 2048 + tid * 8;

    floatx4 acc[7];
#pragma unroll
    for (int t = 0; t < 7; ++t) acc[t] = (floatx4){0.f, 0.f, 0.f, 0.f};

    // prologue: prefetch unit pair (ub, ub+1)
    half8 pb[4];
    float fa0[8], fa1[8];
    {
        const half_t* t0 = ETu + (long)ub * (BROWS * 32);
        pb[0] = *(const half8*)(t0 + goff0);
        pb[1] = *(const half8*)(t0 + goff1);
        pb[2] = *(const half8*)(t0 + BROWS * 32 + goff0);
        pb[3] = *(const half8*)(t0 + BROWS * 32 + goff1);
        __builtin_memcpy(fa0, wrow + ub * 32 + quad * 8, 32);
        __builtin_memcpy(fa1, wrow + (ub + 1) * 32 + quad * 8, 32);
    }

    for (int ip = 0; ip < np; ++ip) {
        // stage current pair
        *(half8*)(&Bs[ip & 1][0][soff0]) = pb[0];
        *(half8*)(&Bs[ip & 1][0][soff1]) = pb[1];
        *(half8*)(&Bs[ip & 1][1][soff0]) = pb[2];
        *(half8*)(&Bs[ip & 1][1][soff1]) = pb[3];
        // convert current A fragments
        half8 a0, a1;
#pragma unroll
        for (int q = 0; q < 8; ++q) { a0[q] = (half_t)fa0[q]; a1[q] = (half_t)fa1[q]; }
        // prefetch next pair
        if (ip + 1 < np) {
            const int u2 = ub + 2 * ip + 2;
            const half_t* nt = ETu + (long)u2 * (BROWS * 32);
            pb[0] = *(const half8*)(nt + goff0);
            pb[1] = *(const half8*)(nt + goff1);
            pb[2] = *(const half8*)(nt + BROWS * 32 + goff0);
            pb[3] = *(const half8*)(nt + BROWS * 32 + goff1);
            __builtin_memcpy(fa0, wrow + u2 * 32 + quad * 8, 32);
            __builtin_memcpy(fa1, wrow + (u2 + 1) * 32 + quad * 8, 32);
        }
        __syncthreads();
        // compute pair from LDS (dbuf: buffer reused only after next barrier)
        const half_t* bp0 = &Bs[ip & 1][0][row16 * BSTR + quad * 8];
        const half_t* bp1 = &Bs[ip & 1][1][row16 * BSTR + quad * 8];
#pragma unroll
        for (int t = 0; t < 7; ++t) {
            const half8 b = *(const half8*)(bp0 + t * 16 * BSTR);
            acc[t] = __builtin_amdgcn_mfma_f32_16x16x32_f16(a0, b, acc[t], 0, 0, 0);
        }
#pragma unroll
        for (int t = 0; t < 7; ++t) {
            const half8 b = *(const half8*)(bp1 + t * 16 * BSTR);
            acc[t] = __builtin_amdgcn_mfma_f32_16x16x32_f16(a1, b, acc[t], 0, 0, 0);
        }
    }

    half_t* Pk = P + (long)kq * (1024 * 100);
    const int orow0 = mgrp * 64 + wv * 16 + quad * 4;   // C/D: row=(lane>>4)*4+r
#pragma unroll
    for (int t = 0; t < 7; ++t) {
        const int col = t * 16 + row16;                 // C/D: col=lane&15
        if (col < 100) {
#pragma unroll
            for (int r = 0; r < 4; ++r)
                Pk[(orow0 + r) * 100 + col] = (half_t)acc[t][r];
        }
    }
}

// ===========================================================================
// kPost: MbT[100][HSTR] f16:
//   kk<1000 : sum_kq P[kq][kk][e] (f16 slabs) + W[kk][32000]*E[32000][e]
//   kk==1000: vvec[e];   else 0
// ===========================================================================
__global__ __launch_bounds__(256) void kPost(const half_t* __restrict__ P,
                                             const float* __restrict__ W,
                                             const float* __restrict__ E,
                                             const float* __restrict__ vvec,
                                             half_t* __restrict__ MbT)
{
    const int idx = blockIdx.x * 256 + threadIdx.x;   // < 1024*100
    const int kk  = idx / 100;
    const int e   = idx - kk * 100;
    float s;
    if (kk < 1000) {
        s = 0.f;
#pragma unroll 9
        for (int kb = 0; kb < NKB; ++kb)
            s += (float)P[(long)kb * (1024 * 100) + kk * 100 + e];
        s += W[(long)kk * V1 + 32000] * E[32000 * 100 + e];
    } else if (kk == 1000) {
        s = vvec[e];
    } else {
        s = 0.f;
    }
    MbT[e * HSTR + kk] = (half_t)s;
}

// ===========================================================================
// kC: out[1600][100] = [h1|1] @ [M;v] via f16 MFMA.
// Grid (100 rb, 4 ks): block = 4 waves x 2 units, LDS reduce, wave 0
// atomicAdds into zero-initialized out.
// ===========================================================================
__global__ __launch_bounds__(256) void kC(const half_t* __restrict__ h1h,
                                          const half_t* __restrict__ MbT,
                                          float* __restrict__ out)
{
    __shared__ float red[3][64][29];
    const int tid   = threadIdx.x;
    const int lane  = tid & 63;
    const int wv    = tid >> 6;
    const int rb    = blockIdx.x;          // 0..99
    const int ks    = blockIdx.y;          // 0..3
    const int row16 = lane & 15;
    const int quad  = lane >> 4;

    const half_t* arow = h1h + (long)(rb * 16 + row16) * HSTR + quad * 8;
    const half_t* bbase[7];
#pragma unroll
    for (int t = 0; t < 7; ++t) {
        const int nc = min(t * 16 + row16, 99);
        bbase[t] = MbT + (long)nc * HSTR + quad * 8;
    }

    floatx4 acc[7];
#pragma unroll
    for (int t = 0; t < 7; ++t) acc[t] = (floatx4){0.f, 0.f, 0.f, 0.f};

    const int wb = ks * 8 + wv * 2;
#pragma unroll
    for (int un = wb; un < wb + 2; ++un) {
        const half8 a = *(const half8*)(arow + un * 32);
#pragma unroll
        for (int t = 0; t < 7; ++t) {
            const half8 b = *(const half8*)(bbase[t] + un * 32);
            acc[t] = __builtin_amdgcn_mfma_f32_16x16x32_f16(a, b, acc[t], 0, 0, 0);
        }
    }

    if (wv > 0) {
#pragma unroll
        for (int t = 0; t < 7; ++t)
#pragma unroll
            for (int r = 0; r < 4; ++r)
                red[wv - 1][lane][t * 4 + r] = acc[t][r];
    }
    __syncthreads();
    if (wv == 0) {
        const int orow0 = rb * 16 + quad * 4;
#pragma unroll
        for (int t = 0; t < 7; ++t) {
            const int col = t * 16 + row16;
            if (col < 100) {
#pragma unroll
                for (int r = 0; r < 4; ++r) {
                    const int i = t * 4 + r;
                    const float s = acc[t][r] + red[0][lane][i]
                                  + red[1][lane][i] + red[2][lane][i];
                    atomicAdd(&out[(orow0 + r) * 100 + col], s);
                }
            }
        }
    }
}

// ===========================================================================
extern "C" void kernel_launch(void* const* d_in, const int* in_sizes, int n_in,
                              void* d_out, int out_size, void* d_ws, size_t ws_size,
                              hipStream_t stream)
{
    const int*   target     = (const int*)d_in[1];
    const int*   start_tok  = (const int*)d_in[2];
    const float* emb        = (const float*)d_in[3];
    const float* dec_kernel = (const float*)d_in[7];
    const float* dec_bias   = (const float*)d_in[9];
    const float* fc_w       = (const float*)d_in[10];
    const float* fc_b       = (const float*)d_in[11];

    float*  vvec = (float*)d_ws;                         // 128 f32 (512 B)
    half_t* ETu  = (half_t*)(vvec + 128);                // 1000*128*32 f16 (8.19 MB)
    half_t* h1h  = ETu + (size_t)UNITS * (BROWS * 32);   // 1600*HSTR f16 (3.28 MB)
    half_t* MbT  = h1h + (size_t)NROWS * HSTR;           // 100*HSTR f16 (0.20 MB)
    half_t* P    = MbT + (size_t)100 * HSTR;             // 63*1024*100 f16 (12.9 MB)
    float*  out  = (float*)d_out;                        // total ws ~23.4 MiB

    hipMemsetAsync(vvec, 0, 128 * sizeof(float), stream);
    hipMemsetAsync(out, 0, (size_t)NROWS * EMBD * sizeof(float), stream);

    kPre<<<1556, 256, 0, stream>>>(emb, ETu, fc_b, vvec, target, start_tok,
                                   dec_kernel, dec_bias, h1h);
    kA<<<dim3(16, NKB), 256, 0, stream>>>(fc_w, ETu, P);
    kPost<<<(1024 * 100) / 256, 256, 0, stream>>>(P, fc_w, emb, vvec, MbT);
    kC<<<dim3(100, 4), 256, 0, stream>>>(h1h, MbT, out);
}